// Round 6
// baseline (190.878 us; speedup 1.0000x reference)
//
#include <hip/hip_runtime.h>

// Problem constants (from reference)
#define N_GRAPHS  4096
#define NPG       256      // nodes per graph (contiguous batch segments)
#define F_IN      16
#define HID       32
#define LOG2E     1.4426950408889634f

typedef _Float16 half8  __attribute__((ext_vector_type(8)));   // 4 VGPR MFMA A/B
typedef float    f32x16 __attribute__((ext_vector_type(16)));  // MFMA C/D 32x32

#if __has_builtin(__builtin_amdgcn_exp2f)
#define EXP2(x) __builtin_amdgcn_exp2f(x)
#else
#define EXP2(x) exp2f(x)
#endif

typedef const __attribute__((address_space(1))) void* gptr_t;
typedef __attribute__((address_space(3))) void*       lptr_t;

// One (node, col) activation: omz*tanh merged into a single rcp.
// v = (e2-1) / ((1+e1)*(e2+1)); clamp keeps e2 finite (avoids inf*0 NaN).
__device__ __forceinline__ float gate_term(float az, float ah, float wl, float osum)
{
    const float e1 = EXP2(az);
    const float e2 = EXP2(fminf(ah, 126.0f));
    const float r  = __builtin_amdgcn_rcpf((1.0f + e1) * (e2 + 1.0f));
    float v = (e2 - 1.0f) * r;
    v = v > 0.0f ? v : 0.0f;                 // relu (omz>0, sign is tanh's)
    return fmaf(v, wl, osum);
}

// One 32-node tile: hi/lo f32->f16 split via two chained MFMAs per gate.
// A layout: lane l holds node (tile + (l&31)), features (l>>5)*8 .. +8.
// C/D layout (HW-verified): col = lane&31, rows bijective over 0..31.
__device__ __forceinline__ float tile32(float4 c0, float4 c1,
    half8 Bz, half8 Bh, float bzl, float bhl, float wll, float osum)
{
    const float xf[8] = { c0.x, c0.y, c0.z, c0.w, c1.x, c1.y, c1.z, c1.w };
    half8 Ah, Al;
#pragma unroll
    for (int j = 0; j < 8; ++j) {
        const _Float16 h = (_Float16)xf[j];            // hi
        Ah[j] = h;
        Al[j] = (_Float16)(xf[j] - (float)h);          // exact residual
    }
    f32x16 accZ, accH;
#pragma unroll
    for (int i = 0; i < 16; ++i) { accZ[i] = bzl; accH[i] = bhl; }
    accZ = __builtin_amdgcn_mfma_f32_32x32x16_f16(Ah, Bz, accZ, 0, 0, 0);
    accH = __builtin_amdgcn_mfma_f32_32x32x16_f16(Ah, Bh, accH, 0, 0, 0);
    accZ = __builtin_amdgcn_mfma_f32_32x32x16_f16(Al, Bz, accZ, 0, 0, 0);
    accH = __builtin_amdgcn_mfma_f32_32x32x16_f16(Al, Bh, accH, 0, 0, 0);
#pragma unroll
    for (int i = 0; i < 16; ++i)
        osum = gate_term(accZ[i], accH[i], wll, osum);
    return osum;
}

// Stage one half-graph (8 KB: 4 tiles x 2 KB) into this wave's LDS buffer.
// Linear dest slot l = node (l&31), floats (l>>5)*8 (+4 for second unit) —
// source address is per-lane, dest is base + lane*16 (both-sides-consistent).
// Per-pair sched_barrier pins VMEM issue order so counted vmcnt stays exact.
#define STAGE(hgi, bufofs) do {                                               \
    _Pragma("unroll")                                                         \
    for (int tau = 0; tau < 4; ++tau) {                                       \
        const float* src_ = xw_base + (hgi) * 2048 + tau * 512 + gu;          \
        __builtin_amdgcn_global_load_lds((gptr_t)src_,                        \
            (lptr_t)(xs_wave + (bufofs) + tau * 512), 16, 0, 0);              \
        __builtin_amdgcn_global_load_lds((gptr_t)(src_ + 4),                  \
            (lptr_t)(xs_wave + (bufofs) + tau * 512 + 256), 16, 0, 0);        \
        __builtin_amdgcn_sched_barrier(0);                                    \
    }                                                                         \
} while (0)

// Wait for tile tau's 2 staging loads (counted, in-order retirement), then
// consume it. NW is a literal; sched_barrier stops hoisting above the wait.
#define TILE_AT(bufofs, tau, NW, ACC) do {                                    \
    asm volatile("s_waitcnt vmcnt(" #NW ")" ::: "memory");                    \
    __builtin_amdgcn_sched_barrier(0);                                        \
    const float4 c0_ = *(const float4*)(xs_wave + (bufofs) + (tau) * 512 + lane * 4);        \
    const float4 c1_ = *(const float4*)(xs_wave + (bufofs) + (tau) * 512 + 256 + lane * 4);  \
    ACC = tile32(c0_, c1_, Bz, Bh, bzl, bhl, wll, ACC);                       \
} while (0)

// Persistent double-buffered pipeline: 512 blocks (2/CU, LDS-capped), each
// wave owns 4 consecutive half-graphs (= graphs 2w, 2w+1). The next 8 KB is
// always in flight during compute, so HBM never idles and the ~900-cyc head
// latency is paid once per wave (not once per 8-KB block generation).
__global__ __launch_bounds__(256, 2) void gcn_fused(
    const float* __restrict__ x,
    const float* __restrict__ Wz, const float* __restrict__ bz,
    const float* __restrict__ Wh, const float* __restrict__ bh,
    const float* __restrict__ Wlin, const float* __restrict__ blin,
    float* __restrict__ out)
{
    __shared__ __attribute__((aligned(16))) float xs[4 * 4096];  // 64 KB: 4 waves x 2 bufs x 8 KB
    const int t = threadIdx.x, wv = t >> 6, lane = t & 63;
    const int col = lane & 31, p = lane >> 5;
    const int wave_id = blockIdx.x * 4 + wv;          // 2048 waves total
    float* xs_wave = xs + wv * 4096;                  // bufA = +0, bufB = +2048
    const float* xw_base = x + (size_t)wave_id * 8192;  // 512 nodes x 16 floats
    const int gu = col * 16 + p * 8;                  // node col, floats p*8..+3

    // ---- section 1: ISSUE weight loads (L2-hot; math deferred below) ----
    float z0[8], z1[8], h0[8], h1[8];
#pragma unroll
    for (int j = 0; j < 8; ++j) {
        const int k = p * 8 + j;
        z0[j] = Wz[k * 32 + col];
        z1[j] = Wz[1536 + k * 32 + col];     // second diffusion direction
        h0[j] = Wh[k * 32 + col];
        h1[j] = Wh[1536 + k * 32 + col];
    }
    const float bz_raw = bz[col], bh_raw = bh[col];
    const float wll = Wlin[col], bl = blin[0];
    __builtin_amdgcn_sched_barrier(0);

    // ---- section 2: prologue staging — fill both buffers' flight ----
    STAGE(0, 0);                                      // hg0 -> bufA
    STAGE(1, 2048);                                   // hg1 -> bufB  (16 outstanding)

    // ---- section 3: weight math under staging flight ----
    half8 Bz, Bh;
#pragma unroll
    for (int j = 0; j < 8; ++j) {
        Bz[j] = (_Float16)((z0[j] + z1[j]) * LOG2E);
        Bh[j] = (_Float16)((h0[j] + h1[j]) * (2.0f * LOG2E));
    }
    const float bzl = bz_raw * LOG2E;
    const float bhl = bh_raw * (2.0f * LOG2E);

    // ---- section 4: compute/stage interleave, counted vmcnt throughout ----
    float osA = 0.0f, osB = 0.0f;                     // graph 2w, graph 2w+1

    TILE_AT(0, 0, 14, osA); TILE_AT(0, 1, 12, osA);   // hg0 (graph A half 0)
    TILE_AT(0, 2, 10, osA); TILE_AT(0, 3,  8, osA);
    STAGE(2, 0);                                      // hg2 -> bufA (reads done)

    TILE_AT(2048, 0, 14, osA); TILE_AT(2048, 1, 12, osA);   // hg1 (graph A half 1)
    TILE_AT(2048, 2, 10, osA); TILE_AT(2048, 3,  8, osA);
    STAGE(3, 2048);                                   // hg3 -> bufB

    TILE_AT(0, 0, 14, osB); TILE_AT(0, 1, 12, osB);   // hg2 (graph B half 0)
    TILE_AT(0, 2, 10, osB); TILE_AT(0, 3,  8, osB);

    TILE_AT(2048, 0, 6, osB); TILE_AT(2048, 1, 4, osB);     // hg3 (graph B half 1)
    TILE_AT(2048, 2, 2, osB); TILE_AT(2048, 3, 0, osB);

    // ---- wave-local reduction: both graphs live in this wave ----
#pragma unroll
    for (int off = 32; off > 0; off >>= 1) {
        osA += __shfl_down(osA, off, 64);
        osB += __shfl_down(osB, off, 64);
    }
    if (lane == 0) {
        float2 o;
        o.x = osA * (1.0f / (float)NPG) + bl;
        o.y = osB * (1.0f / (float)NPG) + bl;
        *(float2*)(out + wave_id * 2) = o;
    }
}

extern "C" void kernel_launch(void* const* d_in, const int* in_sizes, int n_in,
                              void* d_out, int out_size, void* d_ws, size_t ws_size,
                              hipStream_t stream)
{
    // 0:x 1:edge_index 2:edge_weight 3:batch 4:W_z 5:b_z 6:W_r 7:b_r 8:W_h 9:b_h 10:W_lin 11:b_lin
    const float* x    = (const float*)d_in[0];
    const float* Wz   = (const float*)d_in[4];
    const float* bz   = (const float*)d_in[5];
    const float* Wh   = (const float*)d_in[8];
    const float* bh   = (const float*)d_in[9];
    const float* Wlin = (const float*)d_in[10];
    const float* blin = (const float*)d_in[11];
    float* out = (float*)d_out;
    (void)d_ws; (void)ws_size;               // no workspace, single launch

    gcn_fused<<<N_GRAPHS / 8, 256, 0, stream>>>(x, Wz, bz, Wh, bh, Wlin, blin, out);
}

// Round 7
// 171.292 us; speedup vs baseline: 1.1143x; 1.1143x over previous
//
#include <hip/hip_runtime.h>

// Problem constants (from reference)
#define N_GRAPHS  4096
#define NPG       256      // nodes per graph (contiguous batch segments)
#define F_IN      16
#define HID       32
#define LOG2E     1.4426950408889634f

typedef _Float16 half8  __attribute__((ext_vector_type(8)));   // 4 VGPR MFMA A/B
typedef float    f32x16 __attribute__((ext_vector_type(16)));  // MFMA C/D 32x32

#if __has_builtin(__builtin_amdgcn_exp2f)
#define EXP2(x) __builtin_amdgcn_exp2f(x)
#else
#define EXP2(x) exp2f(x)
#endif

typedef const __attribute__((address_space(1))) void* gptr_t;
typedef __attribute__((address_space(3))) void*       lptr_t;

// One (node, col) activation: omz*tanh merged into a single rcp.
// v = (e2-1) / ((1+e1)*(e2+1)); clamp keeps e2 finite (avoids inf*0 NaN).
__device__ __forceinline__ float gate_term(float az, float ah, float wl, float osum)
{
    const float e1 = EXP2(az);
    const float e2 = EXP2(fminf(ah, 126.0f));
    const float r  = __builtin_amdgcn_rcpf((1.0f + e1) * (e2 + 1.0f));
    float v = (e2 - 1.0f) * r;
    v = v > 0.0f ? v : 0.0f;                 // relu (omz>0, sign is tanh's)
    return fmaf(v, wl, osum);
}

// One 32-node tile: hi/lo f32->f16 split via two chained MFMAs per gate.
// A layout: lane l holds node (tile + (l&31)), features (l>>5)*8 .. +8.
// C/D layout (HW-verified): col = lane&31, rows bijective over 0..31.
__device__ __forceinline__ float tile32(float4 c0, float4 c1,
    half8 Bz, half8 Bh, float bzl, float bhl, float wll, float osum)
{
    const float xf[8] = { c0.x, c0.y, c0.z, c0.w, c1.x, c1.y, c1.z, c1.w };
    half8 Ah, Al;
#pragma unroll
    for (int j = 0; j < 8; ++j) {
        const _Float16 h = (_Float16)xf[j];            // hi
        Ah[j] = h;
        Al[j] = (_Float16)(xf[j] - (float)h);          // exact residual
    }
    f32x16 accZ, accH;
#pragma unroll
    for (int i = 0; i < 16; ++i) { accZ[i] = bzl; accH[i] = bhl; }
    accZ = __builtin_amdgcn_mfma_f32_32x32x16_f16(Ah, Bz, accZ, 0, 0, 0);
    accH = __builtin_amdgcn_mfma_f32_32x32x16_f16(Ah, Bh, accH, 0, 0, 0);
    accZ = __builtin_amdgcn_mfma_f32_32x32x16_f16(Al, Bz, accZ, 0, 0, 0);
    accH = __builtin_amdgcn_mfma_f32_32x32x16_f16(Al, Bh, accH, 0, 0, 0);
#pragma unroll
    for (int i = 0; i < 16; ++i)
        osum = gate_term(accZ[i], accH[i], wll, osum);
    return osum;
}

// Stage one 4 KB chunk (2 tiles of 32 nodes) into this wave's LDS buffer.
// 4 x global_load_lds width-16; linear dest slot l = node (l&31), floats
// (l>>5)*8 (+4 for the second 1 KB unit) — source per-lane, dest base+l*16
// (both-sides-consistent). ONE fence per chunk pins group issue order so the
// counted vmcnt below stays exact (not per-pair — r6's per-pair fencing
// caused a 55 MB scratch spill).
#define STAGE_CHUNK(cidx, bufofs) do {                                        \
    const float* s_ = gb + (cidx) * 1024 + gu;                                \
    __builtin_amdgcn_global_load_lds((gptr_t)(s_),                            \
        (lptr_t)(xsw + (bufofs)),       16, 0, 0);                            \
    __builtin_amdgcn_global_load_lds((gptr_t)(s_ + 4),                        \
        (lptr_t)(xsw + (bufofs) + 256), 16, 0, 0);                            \
    __builtin_amdgcn_global_load_lds((gptr_t)(s_ + 512),                      \
        (lptr_t)(xsw + (bufofs) + 512), 16, 0, 0);                            \
    __builtin_amdgcn_global_load_lds((gptr_t)(s_ + 516),                      \
        (lptr_t)(xsw + (bufofs) + 768), 16, 0, 0);                            \
    __builtin_amdgcn_sched_barrier(0);                                        \
} while (0)

// Wait (counted, in-order retirement) for a chunk's 4 loads, then consume
// its 2 tiles. "memory" clobber keeps the ds_reads below the wait.
#define COMPUTE_CHUNK(bufofs, NW) do {                                        \
    asm volatile("s_waitcnt vmcnt(" #NW ")" ::: "memory");                    \
    __builtin_amdgcn_sched_barrier(0);                                        \
    { const float4 c0_ = *(const float4*)(xsw + (bufofs) + lane * 4);         \
      const float4 c1_ = *(const float4*)(xsw + (bufofs) + 256 + lane * 4);   \
      osum = tile32(c0_, c1_, Bz, Bh, bzl, bhl, wll, osum); }                 \
    { const float4 c0_ = *(const float4*)(xsw + (bufofs) + 512 + lane * 4);   \
      const float4 c1_ = *(const float4*)(xsw + (bufofs) + 768 + lane * 4);   \
      osum = tile32(c0_, c1_, Bz, Bh, bzl, bhl, wll, osum); }                 \
} while (0)

// ds_reads of the buffer being overwritten must retire before re-staging.
#define RESTAGE_FENCE() asm volatile("s_waitcnt lgkmcnt(0)" ::: "memory")

// One wave = one whole graph (16 KB = 4 chunks), double-buffered chunk
// stream: chunk c+1 is always in flight while chunk c computes, so each
// wave keeps 4-8 KB outstanding its entire life. Grid = 1024 blocks = the
// ENTIRE grid resident (4 blocks/CU, 16 waves/CU): zero block churn, one
// tail, and 4 waves/SIMD to cover residual waits.
__global__ __launch_bounds__(256, 4) void gcn_fused(
    const float* __restrict__ x,
    const float* __restrict__ Wz, const float* __restrict__ bz,
    const float* __restrict__ Wh, const float* __restrict__ bh,
    const float* __restrict__ Wlin, const float* __restrict__ blin,
    float* __restrict__ out)
{
    __shared__ __attribute__((aligned(16))) float xs[4 * 2048];  // 32 KB: 4 waves x 2 bufs x 4 KB
    const int t = threadIdx.x, wv = t >> 6, lane = t & 63;
    const int col = lane & 31, p = lane >> 5;
    const int g = blockIdx.x * 4 + wv;                // wave -> graph
    float* xsw = xs + wv * 2048;                      // buf0 = +0, buf1 = +1024
    const float* gb = x + (size_t)g * (NPG * F_IN);   // 4096 floats per graph
    const int gu = col * 16 + p * 8;                  // node col, floats p*8..+3

    // Weights: load AND fold now (one-time, L2-hot after the first blocks;
    // no long-lived raw-weight arrays across fences -> no spill pressure).
    half8 Bz, Bh;
#pragma unroll
    for (int j = 0; j < 8; ++j) {
        const int k = p * 8 + j;
        Bz[j] = (_Float16)((Wz[k * 32 + col] + Wz[1536 + k * 32 + col]) * LOG2E);
        Bh[j] = (_Float16)((Wh[k * 32 + col] + Wh[1536 + k * 32 + col]) * (2.0f * LOG2E));
    }
    const float bzl = bz[col] * LOG2E;
    const float bhl = bh[col] * (2.0f * LOG2E);
    const float wll = Wlin[col], bl = blin[0];

    // Drain weight loads so staging-load counting below is exact.
    asm volatile("s_waitcnt vmcnt(0)" ::: "memory");
    __builtin_amdgcn_sched_barrier(0);

    float osum = 0.0f;
    STAGE_CHUNK(0, 0);                    // outstanding 4
    STAGE_CHUNK(1, 1024);                 // outstanding 8
    COMPUTE_CHUNK(0, 4);                  // chunk0 ready (chunk1 in flight)
    RESTAGE_FENCE();
    STAGE_CHUNK(2, 0);                    // refill buf0 under compute
    COMPUTE_CHUNK(1024, 4);               // chunk1 ready (chunk2 in flight)
    RESTAGE_FENCE();
    STAGE_CHUNK(3, 1024);                 // refill buf1 under compute
    COMPUTE_CHUNK(0, 4);                  // chunk2 ready (chunk3 in flight)
    COMPUTE_CHUNK(1024, 0);               // chunk3 ready (final drain)

    // Wave-local butterfly; lane 0 owns the graph's output. No barriers.
#pragma unroll
    for (int off = 32; off > 0; off >>= 1)
        osum += __shfl_down(osum, off, 64);
    if (lane == 0)
        out[g] = osum * (1.0f / (float)NPG) + bl;
}

extern "C" void kernel_launch(void* const* d_in, const int* in_sizes, int n_in,
                              void* d_out, int out_size, void* d_ws, size_t ws_size,
                              hipStream_t stream)
{
    // 0:x 1:edge_index 2:edge_weight 3:batch 4:W_z 5:b_z 6:W_r 7:b_r 8:W_h 9:b_h 10:W_lin 11:b_lin
    const float* x    = (const float*)d_in[0];
    const float* Wz   = (const float*)d_in[4];
    const float* bz   = (const float*)d_in[5];
    const float* Wh   = (const float*)d_in[8];
    const float* bh   = (const float*)d_in[9];
    const float* Wlin = (const float*)d_in[10];
    const float* blin = (const float*)d_in[11];
    float* out = (float*)d_out;
    (void)d_ws; (void)ws_size;               // no workspace, single launch

    gcn_fused<<<N_GRAPHS / 4, 256, 0, stream>>>(x, Wz, bz, Wh, bh, Wlin, blin, out);
}